// Round 4
// baseline (981.361 us; speedup 1.0000x reference)
//
#include <hip/hip_runtime.h>
#include <hip/hip_bf16.h>

// ---- problem constants ----
#define B_   128
#define T_   17
#define E_   512
#define H_   512
#define V_   32000
#define D2_  1024
#define MR_  (B_*T_)   // 2176 rows = 17*128

typedef __attribute__((ext_vector_type(8))) short short8;   // 8 bf16 in 4 VGPRs
typedef __attribute__((ext_vector_type(4))) float f32x4;

__device__ __forceinline__ unsigned short f2b(float f) {   // fp32 -> bf16 RNE
  unsigned u = __float_as_uint(f);
  u += 0x7FFFu + ((u >> 16) & 1u);
  return (unsigned short)(u >> 16);
}
__device__ __forceinline__ float sigf(float x) { return 1.f / (1.f + __expf(-x)); }
__device__ __forceinline__ float tanhfast(float x) {
  x = fminf(fmaxf(x, -15.f), 15.f);
  float e = __expf(2.f * x);
  return (e - 1.f) / (e + 1.f);
}

// async global->LDS, 16B per lane. LDS dest is wave-uniform base + lane*16.
__device__ __forceinline__ void async16(const void* g, void* l) {
  __builtin_amdgcn_global_load_lds((const __attribute__((address_space(1))) unsigned int*)g,
                                   (__attribute__((address_space(3))) unsigned int*)l,
                                   16, 0, 0);
}

// ---------------------------------------------------------------------------
// bf16 MFMA GEMM: C[M x N] = A[M x K] * Bt[N x K]^T (+ epilogue)
// 128x128 tile, 4 waves, 1-D grid, M-block = f % nbm (fastest).
// EPI: 0 = f32 +permuted(bias0+bias1)   2 = bf16 relu(+bias0)
//      3 = bf16 +bias0                  4 = f32 +bias0
// (kept for the small GEMMs; the logits GEMM uses gemm256 below)
// ---------------------------------------------------------------------------
template<int EPI, int SWZ>
__global__ __launch_bounds__(256, 2)
void gemm_bt(const unsigned short* __restrict__ A,
             const unsigned short* __restrict__ Bt,
             void* __restrict__ C,
             const float* __restrict__ bias0,
             const float* __restrict__ bias1,
             int N, int K, int nbm, int nwork)
{
  __shared__ unsigned short sA[128 * 32];
  __shared__ unsigned short sB[128 * 32];

  int f = blockIdx.x;
  if constexpr (SWZ) {
    int per = (nwork + 7) >> 3;
    f = (f & 7) * per + (f >> 3);
    if (f >= nwork) return;
  }
  const size_t bm = (size_t)(f % nbm) * 128;
  const size_t bn = (size_t)(f / nbm) * 128;

  const int tid  = threadIdx.x;
  const int lane = tid & 63;
  const int wave = tid >> 6;
  const int wm   = wave & 1;
  const int wn   = wave >> 1;

  const int sRow   = wave * 32 + (lane >> 2);
  const int gchunk = (lane & 3) ^ ((sRow >> 2) & 3);

  const unsigned short* gA  = A  + (bm + sRow)      * (size_t)K + gchunk * 8;
  const unsigned short* gA2 = A  + (bm + sRow + 16) * (size_t)K + gchunk * 8;
  const unsigned short* gB  = Bt + (bn + sRow)      * (size_t)K + gchunk * 8;
  const unsigned short* gB2 = Bt + (bn + sRow + 16) * (size_t)K + gchunk * 8;

  unsigned short* lA  = &sA[wave * 1024];
  unsigned short* lA2 = &sA[wave * 1024 + 512];
  unsigned short* lB  = &sB[wave * 1024];
  unsigned short* lB2 = &sB[wave * 1024 + 512];

  f32x4 acc[4][4] = {};
  const int fm = lane & 15;
  const int q  = lane >> 4;

  for (int kt = 0; kt < K; kt += 32) {
    async16(gA  + kt, lA);
    async16(gA2 + kt, lA2);
    async16(gB  + kt, lB);
    async16(gB2 + kt, lB2);
    __syncthreads();

    short8 af[4], bfv[4];
#pragma unroll
    for (int i = 0; i < 4; i++) {
      int ra = wm * 64 + i * 16 + fm;
      af[i]  = *(const short8*)&sA[ra * 32 + ((q ^ ((ra >> 2) & 3)) * 8)];
      int rb = wn * 64 + i * 16 + fm;
      bfv[i] = *(const short8*)&sB[rb * 32 + ((q ^ ((rb >> 2) & 3)) * 8)];
    }
#pragma unroll
    for (int i = 0; i < 4; i++)
#pragma unroll
      for (int j = 0; j < 4; j++)
        acc[i][j] = __builtin_amdgcn_mfma_f32_16x16x32_bf16(af[i], bfv[j], acc[i][j], 0, 0, 0);
    __syncthreads();
  }

  // C/D layout: col = lane&15, row = (lane>>4)*4 + reg
#pragma unroll
  for (int i = 0; i < 4; i++) {
#pragma unroll
    for (int j = 0; j < 4; j++) {
      size_t col = bn + wn * 64 + j * 16 + fm;
      float bv = 0.f;
      if constexpr (EPI == 0) {
        size_t oc = ((col & 3) << 9) + (col >> 2);   // un-permute gate col
        bv = bias0[oc] + bias1[oc];
      }
      if constexpr (EPI == 2 || EPI == 3 || EPI == 4) bv = bias0[col];
#pragma unroll
      for (int r = 0; r < 4; r++) {
        size_t row = bm + wm * 64 + i * 16 + q * 4 + r;
        float v = acc[i][j][r] + bv;
        if constexpr (EPI == 2) {
          v = v > 0.f ? v : 0.f;
          ((unsigned short*)C)[row * N + col] = f2b(v);
        } else if constexpr (EPI == 3) {
          ((unsigned short*)C)[row * N + col] = f2b(v);
        } else {
          ((float*)C)[row * N + col] = v;
        }
      }
    }
  }
}

// ---------------------------------------------------------------------------
// 128(M)x256(N)-tile 8-wave pipelined bf16 MFMA GEMM (logits GEMM).
// vs round-3 256x256: M=2176=17*128 exactly -> NO clamp duplication; nwork =
// 17*125 = 2125 blocks -> 8.3 waves of 256 CUs -> grid-tail residency ~92%
// (was 4.39 rounds / 77%).  acc halves to 64 VGPR/wave -> no spill pressure.
// C[M x N] = A[M x K] * Bt[N x K]^T (+bias).  K%128==0 (NT even), N%256==0,
// M%128==0.  Waves: wm = wave>>2 (2 M-halves of 64), wn = wave&3 (4 N-quarters
// of 64); per-wave output 64x64 -> acc[4][4] f32x4.
//
// LDS: 2buf x (A 128x64 + B 256x64) bf16 = 96 KiB, XOR-swizzled chunks
// (chunk' = chunk ^ (row&7)); staging pre-swizzles the GLOBAL source.
// 4 phases per K-tile, one M-frag each, A-frags register-double-buffered
// (af0/af1), B-frags (breg, 32 VGPR) single-buffered, reloaded at p3
// interleaved j-outer between MFMA pairs (register WAR orders the reload
// after the last use; the 10-read LDS burst hides under the MFMA cluster).
// Staging duties (per wave per tile: B 4 instr, A 2 instr):
//   p0: B(t+2) rows   0-127 -> sB[bi] (2)   p1: B(t+2) rows 128-255 (2)
//   p2: A(t+2) rows   0- 63 -> sA[bi] (1)   p3: A(t+2) rows  64-127 (1)
// Tile gate at p2-end: lgkmcnt(0) + vmcnt(5) retires through t-1.p3 =
// ALL of tile t+1 (B issued t-1.p0/p1, A t-1.p2/p3; youngest 3 phases old
// ~900cyc -> L3/HBM latency covered); vmcnt(0) only in the tail.
// WAR at 1-barrier/phase skew: B(t) last read (breg reload) t-1.p3, staged
// over at t.p0 (1 barrier); A(t) q0/q1 read by t-1.p3/t.p0, staged t.p2;
// A(t) q3 read t.p2 (drained at gate), staged t.p3.  RAW: p3's breg/af0
// reads of tile t+1 sit after the p2 gate.  Raw s_barrier only; lgkmcnt(0)
// + sched_barrier(0) before every barrier (rule 18).
// ---------------------------------------------------------------------------
#define STG2(gp, lb, row0, kt) do { \
    async16((gp) + (size_t)(row0) * K + (kt),       (lb) + (row0) * 64); \
    async16((gp) + (size_t)((row0) + 8) * K + (kt), (lb) + ((row0) + 8) * 64); \
  } while (0)

#define STG1(gp, lb, row0, kt) \
    async16((gp) + (size_t)(row0) * K + (kt), (lb) + (row0) * 64)

#define LDA1(dst, sa_, mf_) do { \
    const int r_ = wm * 64 + (mf_) * 16 + fm; \
    dst[0] = *(const short8*)&(sa_)[r_ * 64 + (((q) ^ (r_ & 7)) << 3)]; \
    dst[1] = *(const short8*)&(sa_)[r_ * 64 + (((4 + q) ^ (r_ & 7)) << 3)]; \
  } while (0)

#define LDB(dst, sb_) do { \
    _Pragma("unroll") \
    for (int j = 0; j < 4; j++) { \
      const int r_ = wn * 64 + j * 16 + fm; \
      _Pragma("unroll") \
      for (int ks = 0; ks < 2; ks++) \
        dst[j][ks] = *(const short8*)&(sb_)[r_ * 64 + (((ks * 4 + q) ^ (r_ & 7)) << 3)]; \
    } } while (0)

#define MMA(ab, mf_) do { \
    _Pragma("unroll") \
    for (int j = 0; j < 4; j++) \
      _Pragma("unroll") \
      for (int ks = 0; ks < 2; ks++) \
        acc[mf_][j] = __builtin_amdgcn_mfma_f32_16x16x32_bf16( \
            ab[ks], breg[j][ks], acc[mf_][j], 0, 0, 0); \
  } while (0)

#define PH_TAIL() do { \
    asm volatile("s_waitcnt lgkmcnt(0)" ::: "memory"); \
    __builtin_amdgcn_sched_barrier(0); \
    __builtin_amdgcn_s_barrier(); \
  } while (0)

#define TILE(BI, T) do { \
    const int t_ = (T); \
    const int kt2 = (t_ + 2) << 6; \
    const bool st1 = (t_ + 1) < NT, st2 = (t_ + 2) < NT; \
    /* ---- p0: MMA mf0 | prefetch mf1 | stage B(t+2) lo ---- */ \
    LDA1(af1, sA[BI], 1); \
    if (st2) STG2(gB, sB[BI], brow, kt2); \
    __builtin_amdgcn_sched_barrier(0); \
    __builtin_amdgcn_s_setprio(1); MMA(af0, 0); __builtin_amdgcn_s_setprio(0); \
    PH_TAIL(); \
    /* ---- p1: MMA mf1 | prefetch mf2 | stage B(t+2) hi ---- */ \
    LDA1(af0, sA[BI], 2); \
    if (st2) STG2(gB, sB[BI], brow + 128, kt2); \
    __builtin_amdgcn_sched_barrier(0); \
    __builtin_amdgcn_s_setprio(1); MMA(af1, 1); __builtin_amdgcn_s_setprio(0); \
    PH_TAIL(); \
    /* ---- p2: MMA mf2 | prefetch mf3 | stage A(t+2) lo | GATE ---- */ \
    LDA1(af1, sA[BI], 3); \
    if (st2) STG1(gA, sA[BI], arow, kt2); \
    __builtin_amdgcn_sched_barrier(0); \
    __builtin_amdgcn_s_setprio(1); MMA(af0, 2); __builtin_amdgcn_s_setprio(0); \
    asm volatile("s_waitcnt lgkmcnt(0)" ::: "memory"); \
    if (st2) { asm volatile("s_waitcnt vmcnt(5)" ::: "memory"); } \
    else     { asm volatile("s_waitcnt vmcnt(0)" ::: "memory"); } \
    __builtin_amdgcn_sched_barrier(0); \
    __builtin_amdgcn_s_barrier(); \
    /* ---- p3: MMA mf3 (j-outer, breg(t+1) reload interleaved) | stage A hi */ \
    if (st2) STG1(gA, sA[BI], arow + 64, kt2); \
    __builtin_amdgcn_s_setprio(1); \
    { const unsigned short* sBn = sB[(BI) ^ 1]; \
      _Pragma("unroll") \
      for (int j = 0; j < 4; j++) { \
        acc[3][j] = __builtin_amdgcn_mfma_f32_16x16x32_bf16(af1[0], breg[j][0], acc[3][j], 0, 0, 0); \
        acc[3][j] = __builtin_amdgcn_mfma_f32_16x16x32_bf16(af1[1], breg[j][1], acc[3][j], 0, 0, 0); \
        if (st1) { \
          const int r_ = wn * 64 + j * 16 + fm; \
          breg[j][0] = *(const short8*)&sBn[r_ * 64 + (((q) ^ (r_ & 7)) << 3)]; \
          breg[j][1] = *(const short8*)&sBn[r_ * 64 + (((4 + q) ^ (r_ & 7)) << 3)]; \
        } \
      } } \
    __builtin_amdgcn_s_setprio(0); \
    if (st1) LDA1(af0, sA[(BI) ^ 1], 0); \
    PH_TAIL(); \
  } while (0)

template<int EPI>
__global__ __launch_bounds__(512, 2)
void gemm256(const unsigned short* __restrict__ A,
             const unsigned short* __restrict__ Bt,
             void* __restrict__ C,
             const float* __restrict__ bias0,
             int N, int K, int nbm, int nwork)
{
  __shared__ unsigned short sA[2][128 * 64];
  __shared__ unsigned short sB[2][256 * 64];

  int f = blockIdx.x;
  const int per = (nwork + 7) >> 3;            // XCD-slab swizzle (guarded)
  f = (f & 7) * per + (f >> 3);
  if (f >= nwork) return;
  const size_t bm = (size_t)(f % nbm) * 128;
  const size_t bn = (size_t)(f / nbm) * 256;

  const int tid  = threadIdx.x;
  const int lane = tid & 63;
  const int wave = tid >> 6;                   // 0..7
  const int wm   = wave >> 2;                  // 0..1 (M half of 64)
  const int wn   = wave & 3;                   // 0..3 (N quarter of 64)
  const int fm   = lane & 15;
  const int q    = lane >> 4;

  // per-thread constant source swizzle: staged row r has r&7 == lane>>3,
  // LDS chunk == lane&7, so source chunk = (lane&7) ^ (lane>>3).
  const int cs = (((lane & 7) ^ (lane >> 3)) << 3);
  const unsigned short* gA = A  + (bm + (lane >> 3)) * (size_t)K + cs;
  const unsigned short* gB = Bt + (bn + (lane >> 3)) * (size_t)K + cs;

  const int NT = K >> 6;                       // assumed even, >= 4
  const int arow = wave * 8;                   // A: 8 rows per wave-instr
  const int brow = wave * 16;                  // B: 16 rows per wave (2 instr)

  // prologue: stage tile0 (6 instr/wave) + tile1 (6); vmcnt(6) retires tile0;
  // barrier publishes; preload mf0 frags + breg(tile0).
  STG2(gB, sB[0], brow, 0);
  STG2(gB, sB[0], brow + 128, 0);
  STG1(gA, sA[0], arow, 0);
  STG1(gA, sA[0], arow + 64, 0);
  if (NT > 1) {
    STG2(gB, sB[1], brow, 64);
    STG2(gB, sB[1], brow + 128, 64);
    STG1(gA, sA[1], arow, 64);
    STG1(gA, sA[1], arow + 64, 64);
    asm volatile("s_waitcnt vmcnt(6)" ::: "memory");
  } else {
    asm volatile("s_waitcnt vmcnt(0)" ::: "memory");
  }
  __builtin_amdgcn_s_barrier();

  f32x4 acc[4][4] = {};
  short8 af0[2], af1[2];
  short8 breg[4][2];

  LDA1(af0, sA[0], 0);
  LDB(breg, sB[0]);
  asm volatile("s_waitcnt lgkmcnt(0)" ::: "memory");
  __builtin_amdgcn_sched_barrier(0);

  for (int tt = 0; tt < NT; tt += 2) {
    TILE(0, tt);
    TILE(1, tt + 1);
  }

  // epilogue: col = lane&15, row = (lane>>4)*4 + reg within each 16x16 frag
#pragma unroll
  for (int i = 0; i < 4; i++) {
#pragma unroll
    for (int j = 0; j < 4; j++) {
      const size_t col = bn + wn * 64 + j * 16 + fm;
      const float bv = bias0[col];
#pragma unroll
      for (int r = 0; r < 4; r++) {
        const size_t row = bm + wm * 64 + i * 16 + q * 4 + r;
        const float v = acc[i][j][r] + bv;
        if constexpr (EPI == 3) ((unsigned short*)C)[row * (size_t)N + col] = f2b(v);
        else                    ((float*)C)[row * (size_t)N + col] = v;
      }
    }
  }
}
#undef TILE
#undef PH_TAIL
#undef MMA
#undef LDB
#undef LDA1
#undef STG1
#undef STG2

// ---------------------------------------------------------------------------
// Fused LSTM step: gates = Gt + h_prev @ Whh^T (rows gate-interleaved), then
// pointwise -> c, h. 16 blocks x 128 cols. BK=256 => only 2 K-iters (fewer
// barrier drains on the serial chain). LDS: 2x64KB staging, gate buf aliased.
// ---------------------------------------------------------------------------
__global__ __launch_bounds__(256)
void lstm_step(const unsigned short* __restrict__ hprev,  // 128x512 bf16
               const unsigned short* __restrict__ Whh,    // 2048x512 bf16 permuted
               const float* __restrict__ Gt,              // 128x2048 f32 permuted
               float* __restrict__ c,                     // 128x512 f32
               unsigned short* __restrict__ hout,         // 128x512 bf16
               unsigned short* __restrict__ hsb,          // b-major hs
               int t)
{
  __shared__ char smem[131072];                       // 128 KB
  unsigned short* sA = (unsigned short*)smem;         // 128x256 bf16
  unsigned short* sB = (unsigned short*)(smem + 65536);
  float* gl = (float*)smem;                           // 128x132 f32 (aliased)

  const int tid  = threadIdx.x;
  const int lane = tid & 63;
  const int wave = tid >> 6;
  const int wm   = wave & 1;
  const int wn   = wave >> 1;
  const int n0   = blockIdx.x * 128;

  const int lr = lane >> 5;     // row parity within instruction (2 rows x 32 chunks)
  const int lp = lane & 31;     // LDS chunk position

  f32x4 acc[4][4] = {};
  const int fm = lane & 15;
  const int q  = lane >> 4;

  for (int kt = 0; kt < 512; kt += 256) {
#pragma unroll
    for (int s = 0; s < 16; s++) {
      int row = wave * 32 + s * 2 + lr;           // row within 128-tile
      int gch = lp ^ (row & 7);                   // swizzled global chunk
      async16(hprev + (size_t)row * 512 + kt + gch * 8,
              sA + wave * 8192 + s * 512 + lane * 8);
      async16(Whh + (size_t)(n0 + row) * 512 + kt + gch * 8,
              sB + wave * 8192 + s * 512 + lane * 8);
    }
    __syncthreads();

#pragma unroll
    for (int kk = 0; kk < 8; kk++) {
      int ch = kk * 4 + q;
      short8 af[4], bfv[4];
#pragma unroll
      for (int i = 0; i < 4; i++) {
        int ra = wm * 64 + i * 16 + fm;
        af[i]  = *(const short8*)&sA[ra * 256 + ((ch ^ (ra & 7)) * 8)];
        int rb = wn * 64 + i * 16 + fm;
        bfv[i] = *(const short8*)&sB[rb * 256 + ((ch ^ (rb & 7)) * 8)];
      }
#pragma unroll
      for (int i = 0; i < 4; i++)
#pragma unroll
        for (int j = 0; j < 4; j++)
          acc[i][j] = __builtin_amdgcn_mfma_f32_16x16x32_bf16(af[i], bfv[j], acc[i][j], 0, 0, 0);
    }
    __syncthreads();
  }

  // accumulators -> aliased LDS gate buffer (ld=132 breaks bank alignment)
#pragma unroll
  for (int i = 0; i < 4; i++)
#pragma unroll
    for (int j = 0; j < 4; j++)
#pragma unroll
      for (int r = 0; r < 4; r++)
        gl[(wm * 64 + i * 16 + q * 4 + r) * 132 + wn * 64 + j * 16 + fm] = acc[i][j][r];
  __syncthreads();

  // pointwise: 128 rows x 32 local units (gates interleaved i,f,g,o per unit)
#pragma unroll
  for (int it = 0; it < 16; it++) {
    int p   = it * 256 + tid;
    int row = p >> 5;
    int ul  = p & 31;
    float4 a4 = *(float4*)&gl[row * 132 + ul * 4];
    float4 G4 = *(const float4*)&Gt[row * 2048 + n0 + ul * 4];
    float gi = a4.x + G4.x, gf = a4.y + G4.y, gg = a4.z + G4.z, go = a4.w + G4.w;
    int gu  = (n0 >> 2) + ul;
    int idx = row * 512 + gu;
    float cn = sigf(gf) * c[idx] + sigf(gi) * tanhfast(gg);
    c[idx] = cn;
    float hn = sigf(go) * tanhfast(cn);
    unsigned short h16 = f2b(hn);
    hout[idx] = h16;
    hsb[((size_t)row * T_ + t) * 512 + gu] = h16;
  }
}

// ---- t=0 pointwise (h0=c0=0) ----
__global__ void lstm_point0(const float* __restrict__ G0, float* __restrict__ c,
                            unsigned short* __restrict__ hb, unsigned short* __restrict__ hsb) {
  int idx = blockIdx.x * 256 + threadIdx.x;    // 128*512
  int b = idx >> 9, u = idx & 511;
  float4 g4 = ((const float4*)(G0 + (size_t)b * 2048))[u];
  float cn = sigf(g4.x) * tanhfast(g4.z);
  c[idx] = cn;
  float hn = sigf(g4.w) * tanhfast(cn);
  unsigned short h16 = f2b(hn);
  hb[idx] = h16;
  hsb[((size_t)b * T_ + 0) * 512 + u] = h16;
}

// ---- gate-interleave + bf16 convert for both W_ih and W_hh in one launch ----
__global__ void permute_cvt2(const float* __restrict__ Wih, const float* __restrict__ Whh,
                             unsigned short* __restrict__ dih, unsigned short* __restrict__ dhh) {
  int p = blockIdx.x;                           // 0..4095
  const float* src = (p < 2048) ? Wih : Whh;
  unsigned short* dst = (p < 2048) ? dih : dhh;
  int pp = p & 2047;
  int ir = ((pp & 3) << 9) + (pp >> 2);
  float4 v = ((const float4*)(src + (size_t)ir * 512))[threadIdx.x];   // 128 thr
  ushort4 o;
  o.x = f2b(v.x); o.y = f2b(v.y); o.z = f2b(v.z); o.w = f2b(v.w);
  ((ushort4*)(dst + (size_t)p * 512))[threadIdx.x] = o;
}

// ---- fp32 KxN -> bf16 NxK transpose+convert ----
__global__ void transpose_cvt(const float* __restrict__ src, unsigned short* __restrict__ dst,
                              int K, int N) {
  __shared__ float tile[32][33];
  int n0 = blockIdx.x * 32, k0 = blockIdx.y * 32;
  int tcol = threadIdx.x & 31, trow = threadIdx.x >> 5;
  for (int r = trow; r < 32; r += 8)
    tile[r][tcol] = src[(size_t)(k0 + r) * N + n0 + tcol];
  __syncthreads();
  for (int r = trow; r < 32; r += 8)
    dst[(size_t)(n0 + r) * K + k0 + tcol] = f2b(tile[tcol][r]);
}

// ---- encoder row (t=0 of x) ----
__global__ __launch_bounds__(256) void encode(const float* __restrict__ features,
                                              const float* __restrict__ W_enc,
                                              const float* __restrict__ b_enc,
                                              unsigned short* __restrict__ xb) {
  __shared__ float fs[512];
  int b = blockIdx.y, e = blockIdx.x * 256 + threadIdx.x;
  fs[threadIdx.x]       = features[b * 512 + threadIdx.x];
  fs[threadIdx.x + 256] = features[b * 512 + threadIdx.x + 256];
  __syncthreads();
  float acc = 0.f;
#pragma unroll 8
  for (int k = 0; k < 512; k++) acc += fs[k] * W_enc[(size_t)k * 512 + e];
  xb[(size_t)b * 512 + e] = f2b(acc + b_enc[e]);
}

// ---- embedding gather (t=1..16 of x, time-major) ----
__global__ void embed_k(const int* __restrict__ captions, const float* __restrict__ emb,
                        unsigned short* __restrict__ xb) {
  int t = blockIdx.x + 1, b = blockIdx.y;
  int tok = captions[b * T_ + (t - 1)];
  float4 v = ((const float4*)(emb + (size_t)tok * 512))[threadIdx.x];
  ushort4 o;
  o.x = f2b(v.x); o.y = f2b(v.y); o.z = f2b(v.z); o.w = f2b(v.w);
  ((ushort4*)(xb + (size_t)(t * B_ + b) * 512))[threadIdx.x] = o;
}

// ---- softmax from bf16 logits -> f32 probs ----
__global__ __launch_bounds__(1024) void softmax_b(const unsigned short* __restrict__ lg,
                                                  float* __restrict__ out) {
  __shared__ float ps[1024];
  const uint4* r4 = (const uint4*)(lg + (size_t)blockIdx.x * V_);   // 4000 uint4/row
  float* orow = out + (size_t)blockIdx.x * V_;
  int tid = threadIdx.x;
  float v[4][8];
  float s = 0.f;
#pragma unroll
  for (int u = 0; u < 4; u++) {
    int i = u * 1024 + tid;
    if (i < 4000) {
      uint4 w = r4[i];
      unsigned a[4] = {w.x, w.y, w.z, w.w};
#pragma unroll
      for (int k = 0; k < 4; k++) {
        float lo = __uint_as_float(a[k] << 16);
        float hi = __uint_as_float(a[k] & 0xffff0000u);
        float e0 = __expf(lo), e1 = __expf(hi);
        v[u][2 * k] = e0; v[u][2 * k + 1] = e1;
        s += e0 + e1;
      }
    }
  }
  ps[tid] = s;
  __syncthreads();
  for (int o = 512; o > 0; o >>= 1) {
    if (tid < o) ps[tid] += ps[tid + o];
    __syncthreads();
  }
  float inv = 1.f / ps[0];
#pragma unroll
  for (int u = 0; u < 4; u++) {
    int i = u * 1024 + tid;
    if (i < 4000) {
      float4 o1 = {v[u][0] * inv, v[u][1] * inv, v[u][2] * inv, v[u][3] * inv};
      float4 o2 = {v[u][4] * inv, v[u][5] * inv, v[u][6] * inv, v[u][7] * inv};
      ((float4*)(orow + (size_t)i * 8))[0] = o1;
      ((float4*)(orow + (size_t)i * 8))[1] = o2;
    }
  }
}

// ---- fallback: in-place f32 softmax ----
__global__ __launch_bounds__(1024) void softmax_f(float* __restrict__ out) {
  __shared__ float ps[1024];
  float* r = out + (size_t)blockIdx.x * V_;
  int tid = threadIdx.x;
  float v[32];
  float s = 0.f;
#pragma unroll
  for (int u = 0; u < 32; u++) {
    int i = u * 1024 + tid;
    if (i < V_) { float e = __expf(r[i]); v[u] = e; s += e; }
  }
  ps[tid] = s;
  __syncthreads();
  for (int o = 512; o > 0; o >>= 1) {
    if (tid < o) ps[tid] += ps[tid + o];
    __syncthreads();
  }
  float inv = 1.f / ps[0];
#pragma unroll
  for (int u = 0; u < 32; u++) {
    int i = u * 1024 + tid;
    if (i < V_) r[i] = v[u] * inv;
  }
}

extern "C" void kernel_launch(void* const* d_in, const int* in_sizes, int n_in,
                              void* d_out, int out_size, void* d_ws, size_t ws_size,
                              hipStream_t stream) {
  const float* features = (const float*)d_in[0];
  const int*   captions = (const int*)d_in[1];
  const float* W_enc  = (const float*)d_in[2];
  const float* b_enc  = (const float*)d_in[3];
  const float* emb    = (const float*)d_in[4];
  const float* W_ih   = (const float*)d_in[5];
  const float* b_ih   = (const float*)d_in[6];
  const float* W_hh   = (const float*)d_in[7];
  const float* b_hh   = (const float*)d_in[8];
  const float* W_d2   = (const float*)d_in[9];
  const float* b_d2   = (const float*)d_in[10];
  const float* W_last = (const float*)d_in[11];
  const float* b_last = (const float*)d_in[12];
  float* out = (float*)d_out;

  char* ws = (char*)d_ws;
  size_t off = 0;
  auto alloc = [&](size_t bytes) -> void* {
    void* p = ws + off;
    off += (bytes + 255) & ~(size_t)255;
    return p;
  };
  unsigned short* xb     = (unsigned short*)alloc((size_t)MR_ * E_ * 2);
  unsigned short* Wb_ih  = (unsigned short*)alloc((size_t)4 * H_ * E_ * 2);
  unsigned short* Wb_hh  = (unsigned short*)alloc((size_t)4 * H_ * H_ * 2);
  unsigned short* Wb_d2t = (unsigned short*)alloc((size_t)D2_ * H_ * 2);
  unsigned short* Wb_lt  = (unsigned short*)alloc((size_t)V_ * D2_ * 2);
  float*          G      = (float*)alloc((size_t)MR_ * 4 * H_ * 4);
  float*          cst    = (float*)alloc((size_t)B_ * H_ * 4);
  unsigned short* hb0    = (unsigned short*)alloc((size_t)B_ * H_ * 2);
  unsigned short* hb1    = (unsigned short*)alloc((size_t)B_ * H_ * 2);
  unsigned short* hsb    = (unsigned short*)alloc((size_t)MR_ * H_ * 2);
  unsigned short* outb   = (unsigned short*)alloc((size_t)MR_ * D2_ * 2);
  unsigned short* lgb    = (unsigned short*)alloc((size_t)MR_ * V_ * 2);
  const bool bf16_logits = (off <= ws_size);
  (void)in_sizes; (void)n_in; (void)out_size;

  // weight prep
  permute_cvt2<<<4096, 128, 0, stream>>>(W_ih, W_hh, Wb_ih, Wb_hh);
  transpose_cvt<<<dim3(D2_ / 32, H_ / 32), 256, 0, stream>>>(W_d2, Wb_d2t, H_, D2_);

  // x (bf16, time-major)
  encode<<<dim3(2, B_), 256, 0, stream>>>(features, W_enc, b_enc, xb);
  embed_k<<<dim3(T_ - 1, B_), 128, 0, stream>>>(captions, emb, xb);

  // G = x @ Wb_ih^T + (b_ih + b_hh), gate-interleaved columns
  gemm_bt<0, 0><<<17 * 16, 256, 0, stream>>>(xb, Wb_ih, G, b_ih, b_hh, 4 * H_, E_, 17, 17 * 16);

  // LSTM chain (fused, ping-pong h buffers)
  lstm_point0<<<B_ * H_ / 256, 256, 0, stream>>>(G, cst, hb0, hsb);
  for (int t = 1; t < T_; t++) {
    unsigned short* hp = (t & 1) ? hb0 : hb1;
    unsigned short* hc = (t & 1) ? hb1 : hb0;
    lstm_step<<<16, 256, 0, stream>>>(hp, Wb_hh, G + (size_t)t * B_ * 4 * H_, cst, hc, hsb, t);
  }

  // W_last transpose late so Wb_lt is L2/L3-warm for the big GEMM
  transpose_cvt<<<dim3(V_ / 32, D2_ / 32), 256, 0, stream>>>(W_last, Wb_lt, D2_, V_);

  // out = relu(hs @ W_d2 + b_d2) -> bf16 (b-major rows)
  gemm_bt<2, 0><<<17 * 8, 256, 0, stream>>>(hsb, Wb_d2t, outb, b_d2, nullptr, D2_, H_, 17, 17 * 8);

  // logits = out @ W_last + b_last: 128x256-tile pipelined GEMM, then softmax
  const int nbm2   = 17;                           // 2176/128 exact, no clamp
  const int nwork2 = nbm2 * (V_ / 256);            // 2125
  const int per2   = (nwork2 + 7) / 8;             // 266
  if (bf16_logits) {
    gemm256<3><<<8 * per2, 512, 0, stream>>>(outb, Wb_lt, lgb, b_last, V_, D2_, nbm2, nwork2);
    softmax_b<<<MR_, 1024, 0, stream>>>(lgb, out);
  } else {
    gemm256<4><<<8 * per2, 512, 0, stream>>>(outb, Wb_lt, out, b_last, V_, D2_, nbm2, nwork2);
    softmax_f<<<MR_, 1024, 0, stream>>>(out);
  }
}

// Round 5
// 859.538 us; speedup vs baseline: 1.1417x; 1.1417x over previous
//
#include <hip/hip_runtime.h>
#include <hip/hip_bf16.h>

// ---- problem constants ----
#define B_   128
#define T_   17
#define E_   512
#define H_   512
#define V_   32000
#define D2_  1024
#define MR_  (B_*T_)   // 2176 rows = 17*128

typedef __attribute__((ext_vector_type(8))) short short8;   // 8 bf16 in 4 VGPRs
typedef __attribute__((ext_vector_type(4))) float f32x4;

__device__ __forceinline__ unsigned short f2b(float f) {   // fp32 -> bf16 RNE
  unsigned u = __float_as_uint(f);
  u += 0x7FFFu + ((u >> 16) & 1u);
  return (unsigned short)(u >> 16);
}
__device__ __forceinline__ float sigf(float x) { return 1.f / (1.f + __expf(-x)); }
__device__ __forceinline__ float tanhfast(float x) {
  x = fminf(fmaxf(x, -15.f), 15.f);
  float e = __expf(2.f * x);
  return (e - 1.f) / (e + 1.f);
}

// async global->LDS, 16B per lane. LDS dest is wave-uniform base + lane*16.
__device__ __forceinline__ void async16(const void* g, void* l) {
  __builtin_amdgcn_global_load_lds((const __attribute__((address_space(1))) unsigned int*)g,
                                   (__attribute__((address_space(3))) unsigned int*)l,
                                   16, 0, 0);
}

// ---------------------------------------------------------------------------
// bf16 MFMA GEMM: C[M x N] = A[M x K] * Bt[N x K]^T (+ epilogue)
// 128x128 tile, 4 waves, 1-D grid, M-block = f % nbm (fastest).
// EPI: 0 = f32 +permuted(bias0+bias1)   2 = bf16 relu(+bias0)
//      3 = bf16 +bias0                  4 = f32 +bias0
// (kept for the small GEMMs; the logits GEMM uses gemm256 below)
// ---------------------------------------------------------------------------
template<int EPI, int SWZ>
__global__ __launch_bounds__(256, 2)
void gemm_bt(const unsigned short* __restrict__ A,
             const unsigned short* __restrict__ Bt,
             void* __restrict__ C,
             const float* __restrict__ bias0,
             const float* __restrict__ bias1,
             int N, int K, int nbm, int nwork)
{
  __shared__ unsigned short sA[128 * 32];
  __shared__ unsigned short sB[128 * 32];

  int f = blockIdx.x;
  if constexpr (SWZ) {
    int per = (nwork + 7) >> 3;
    f = (f & 7) * per + (f >> 3);
    if (f >= nwork) return;
  }
  const size_t bm = (size_t)(f % nbm) * 128;
  const size_t bn = (size_t)(f / nbm) * 128;

  const int tid  = threadIdx.x;
  const int lane = tid & 63;
  const int wave = tid >> 6;
  const int wm   = wave & 1;
  const int wn   = wave >> 1;

  const int sRow   = wave * 32 + (lane >> 2);
  const int gchunk = (lane & 3) ^ ((sRow >> 2) & 3);

  const unsigned short* gA  = A  + (bm + sRow)      * (size_t)K + gchunk * 8;
  const unsigned short* gA2 = A  + (bm + sRow + 16) * (size_t)K + gchunk * 8;
  const unsigned short* gB  = Bt + (bn + sRow)      * (size_t)K + gchunk * 8;
  const unsigned short* gB2 = Bt + (bn + sRow + 16) * (size_t)K + gchunk * 8;

  unsigned short* lA  = &sA[wave * 1024];
  unsigned short* lA2 = &sA[wave * 1024 + 512];
  unsigned short* lB  = &sB[wave * 1024];
  unsigned short* lB2 = &sB[wave * 1024 + 512];

  f32x4 acc[4][4] = {};
  const int fm = lane & 15;
  const int q  = lane >> 4;

  for (int kt = 0; kt < K; kt += 32) {
    async16(gA  + kt, lA);
    async16(gA2 + kt, lA2);
    async16(gB  + kt, lB);
    async16(gB2 + kt, lB2);
    __syncthreads();

    short8 af[4], bfv[4];
#pragma unroll
    for (int i = 0; i < 4; i++) {
      int ra = wm * 64 + i * 16 + fm;
      af[i]  = *(const short8*)&sA[ra * 32 + ((q ^ ((ra >> 2) & 3)) * 8)];
      int rb = wn * 64 + i * 16 + fm;
      bfv[i] = *(const short8*)&sB[rb * 32 + ((q ^ ((rb >> 2) & 3)) * 8)];
    }
#pragma unroll
    for (int i = 0; i < 4; i++)
#pragma unroll
      for (int j = 0; j < 4; j++)
        acc[i][j] = __builtin_amdgcn_mfma_f32_16x16x32_bf16(af[i], bfv[j], acc[i][j], 0, 0, 0);
    __syncthreads();
  }

  // C/D layout: col = lane&15, row = (lane>>4)*4 + reg
#pragma unroll
  for (int i = 0; i < 4; i++) {
#pragma unroll
    for (int j = 0; j < 4; j++) {
      size_t col = bn + wn * 64 + j * 16 + fm;
      float bv = 0.f;
      if constexpr (EPI == 0) {
        size_t oc = ((col & 3) << 9) + (col >> 2);   // un-permute gate col
        bv = bias0[oc] + bias1[oc];
      }
      if constexpr (EPI == 2 || EPI == 3 || EPI == 4) bv = bias0[col];
#pragma unroll
      for (int r = 0; r < 4; r++) {
        size_t row = bm + wm * 64 + i * 16 + q * 4 + r;
        float v = acc[i][j][r] + bv;
        if constexpr (EPI == 2) {
          v = v > 0.f ? v : 0.f;
          ((unsigned short*)C)[row * N + col] = f2b(v);
        } else if constexpr (EPI == 3) {
          ((unsigned short*)C)[row * N + col] = f2b(v);
        } else {
          ((float*)C)[row * N + col] = v;
        }
      }
    }
  }
}

// ---------------------------------------------------------------------------
// 256x256-tile 8-wave pipelined bf16 MFMA GEMM (round-3 verified version).
// A-frags register-double-buffered, B-frags single-buffered (reloaded at p3
// after MFMA issue).  ONE barrier per phase (4/K-tile); tile gate vmcnt(4)
// at p2; never vmcnt(0) in the steady loop.  See round-3 notes for the
// WAR/RAW proofs.  Round-4's 128x256 retile REGRESSED (B-panel HBM re-fetch
// +72MB, phase overhead fraction doubled) -- do not re-tile without fixing
// both.
// ---------------------------------------------------------------------------
#define STG(gp, lb, row0, kt) do { \
    async16((gp) + (size_t)(row0) * K + (kt),       (lb) + (row0) * 64); \
    async16((gp) + (size_t)((row0) + 8) * K + (kt), (lb) + ((row0) + 8) * 64); \
  } while (0)

#define LDA(dst, sa_, mq_) do { \
    _Pragma("unroll") \
    for (int ff = 0; ff < 2; ff++) { \
      const int r_ = wm * 128 + ((mq_) * 2 + ff) * 16 + fm; \
      _Pragma("unroll") \
      for (int ks = 0; ks < 2; ks++) \
        dst[ff][ks] = *(const short8*)&(sa_)[r_ * 64 + (((ks * 4 + q) ^ (r_ & 7)) << 3)]; \
    } } while (0)

#define LDB(dst, sb_) do { \
    _Pragma("unroll") \
    for (int j = 0; j < 4; j++) { \
      const int r_ = wn * 64 + j * 16 + fm; \
      _Pragma("unroll") \
      for (int ks = 0; ks < 2; ks++) \
        dst[j][ks] = *(const short8*)&(sb_)[r_ * 64 + (((ks * 4 + q) ^ (r_ & 7)) << 3)]; \
    } } while (0)

#define MMA(ab, mq_) do { \
    _Pragma("unroll") \
    for (int ff = 0; ff < 2; ff++) \
      _Pragma("unroll") \
      for (int j = 0; j < 4; j++) \
        _Pragma("unroll") \
        for (int ks = 0; ks < 2; ks++) \
          acc[(mq_) * 2 + ff][j] = __builtin_amdgcn_mfma_f32_16x16x32_bf16( \
              ab[ff][ks], breg[j][ks], acc[(mq_) * 2 + ff][j], 0, 0, 0); \
  } while (0)

#define PH_TAIL() do { \
    asm volatile("s_waitcnt lgkmcnt(0)" ::: "memory"); \
    __builtin_amdgcn_sched_barrier(0); \
    __builtin_amdgcn_s_barrier(); \
  } while (0)

#define TILE(BI, T) do { \
    const int t_ = (T); \
    const int kt1 = (t_ + 1) << 6, kt2 = (t_ + 2) << 6; \
    const bool st1 = (t_ + 1) < NT, st2 = (t_ + 2) < NT; \
    /* ---- p0 ---- */ \
    LDA(af1, sA[BI], 1); \
    if (st1) STG(gA, sA[(BI) ^ 1], arow1, kt1); \
    __builtin_amdgcn_sched_barrier(0); \
    __builtin_amdgcn_s_setprio(1); MMA(af0, 0); __builtin_amdgcn_s_setprio(0); \
    PH_TAIL(); \
    /* ---- p1 ---- */ \
    LDA(af0, sA[BI], 2); \
    if (st2) STG(gB, sB[BI], brow0, kt2); \
    __builtin_amdgcn_sched_barrier(0); \
    __builtin_amdgcn_s_setprio(1); MMA(af1, 1); __builtin_amdgcn_s_setprio(0); \
    PH_TAIL(); \
    /* ---- p2 (tile gate) ---- */ \
    LDA(af1, sA[BI], 3); \
    if (st2) STG(gB, sB[BI], brow1, kt2); \
    __builtin_amdgcn_sched_barrier(0); \
    __builtin_amdgcn_s_setprio(1); MMA(af0, 2); __builtin_amdgcn_s_setprio(0); \
    asm volatile("s_waitcnt lgkmcnt(0)" ::: "memory"); \
    if (st2) { asm volatile("s_waitcnt vmcnt(4)" ::: "memory"); } \
    else     { asm volatile("s_waitcnt vmcnt(0)" ::: "memory"); } \
    __builtin_amdgcn_sched_barrier(0); \
    __builtin_amdgcn_s_barrier(); \
    /* ---- p3 ---- */ \
    if (st1) LDA(af0, sA[(BI) ^ 1], 0); \
    if (st2) STG(gA, sA[BI], arow0, kt2); \
    __builtin_amdgcn_sched_barrier(0); \
    __builtin_amdgcn_s_setprio(1); MMA(af1, 3); __builtin_amdgcn_s_setprio(0); \
    if (st1) LDB(breg, sB[(BI) ^ 1]); \
    PH_TAIL(); \
  } while (0)

template<int EPI>
__global__ __launch_bounds__(512, 2)
void gemm256(const unsigned short* __restrict__ A,
             const unsigned short* __restrict__ Bt,
             void* __restrict__ C,
             const float* __restrict__ bias0,
             int N, int K, int M, int nbm, int nwork)
{
  __shared__ unsigned short sA[2][256 * 64];
  __shared__ unsigned short sB[2][256 * 64];

  int f = blockIdx.x;
  const int per = (nwork + 7) >> 3;            // XCD-slab swizzle (guarded)
  f = (f & 7) * per + (f >> 3);
  if (f >= nwork) return;
  int bmx = (f % nbm) * 256;
  if (bmx > M - 256) bmx = M - 256;            // clamp: duplicate rows benign
  const size_t bm = (size_t)bmx;
  const size_t bn = (size_t)(f / nbm) * 256;

  const int tid  = threadIdx.x;
  const int lane = tid & 63;
  const int wave = tid >> 6;                   // 0..7
  const int wm   = wave >> 2;                  // 0..1 (M half)
  const int wn   = wave & 3;                   // 0..3 (N quarter)
  const int fm   = lane & 15;
  const int q    = lane >> 4;

  // per-thread constant source swizzle: staged row r has r&7 == lane>>3,
  // LDS chunk == lane&7, so source chunk = (lane&7) ^ (lane>>3).
  const int cs = (((lane & 7) ^ (lane >> 3)) << 3);
  const unsigned short* gA = A  + (bm + (lane >> 3)) * (size_t)K + cs;
  const unsigned short* gB = Bt + (bn + (lane >> 3)) * (size_t)K + cs;

  const int NT = K >> 6;                       // assumed even, >= 4
  const int arow0 = (wave & 3) * 16 + (wave >> 2) * 128;  // A rows {0-63,128-191}
  const int arow1 = arow0 + 64;                            // A rows {64-127,192-255}
  const int brow0 = wave * 16;                             // B rows 0-127
  const int brow1 = brow0 + 128;                           // B rows 128-255

  // prologue: stage tile0 fully, then mimic the t-1.{p1,p2,p3} duties for
  // tile1 (6 loads).  vmcnt(6) retires exactly tile0; barrier publishes;
  // then preload q0 frags + breg(tile0).
  STG(gB, sB[0], brow0, 0);
  STG(gB, sB[0], brow1, 0);
  STG(gA, sA[0], arow0, 0);
  STG(gA, sA[0], arow1, 0);
  if (NT > 1) {
    STG(gB, sB[1], brow0, 64);
    STG(gB, sB[1], brow1, 64);
    STG(gA, sA[1], arow0, 64);
    asm volatile("s_waitcnt vmcnt(6)" ::: "memory");
  } else {
    asm volatile("s_waitcnt vmcnt(0)" ::: "memory");
  }
  __builtin_amdgcn_s_barrier();

  f32x4 acc[8][4] = {};
  short8 af0[2][2], af1[2][2];
  short8 breg[4][2];

  LDA(af0, sA[0], 0);
  LDB(breg, sB[0]);
  asm volatile("s_waitcnt lgkmcnt(0)" ::: "memory");
  __builtin_amdgcn_sched_barrier(0);

  for (int tt = 0; tt < NT; tt += 2) {
    TILE(0, tt);
    TILE(1, tt + 1);
  }

  // epilogue: col = lane&15, row = (lane>>4)*4 + reg within each 16x16 frag
#pragma unroll
  for (int i = 0; i < 8; i++) {
#pragma unroll
    for (int j = 0; j < 4; j++) {
      const size_t col = bn + wn * 64 + j * 16 + fm;
      const float bv = bias0[col];
#pragma unroll
      for (int r = 0; r < 4; r++) {
        const size_t row = bm + wm * 128 + i * 16 + q * 4 + r;
        const float v = acc[i][j][r] + bv;
        if constexpr (EPI == 3) ((unsigned short*)C)[row * (size_t)N + col] = f2b(v);
        else                    ((float*)C)[row * (size_t)N + col] = v;
      }
    }
  }
}
#undef TILE
#undef PH_TAIL
#undef MMA
#undef LDB
#undef LDA
#undef STG

// ---------------------------------------------------------------------------
// Fused LSTM step: gates = Gt + h_prev @ Whh^T (rows gate-interleaved), then
// pointwise -> c, h.  NOW 32 blocks x 64 cols (was 16 x 128): doubles CU
// parallelism on the serial t-chain; per-CU MFMA+staging per step halves.
// Each block reads its exclusive 64-row Whh slice (no duplication) + full
// hprev (128 KB, L2-hot).  BK=256 => 2 K-iters.  LDS 96 KB: sA 128x256
// (64 KB) + sB 64x256 (32 KB); f32 gate buf (ld=68 breaks bank alignment)
// aliased over sA.
// ---------------------------------------------------------------------------
__global__ __launch_bounds__(256)
void lstm_step(const unsigned short* __restrict__ hprev,  // 128x512 bf16
               const unsigned short* __restrict__ Whh,    // 2048x512 bf16 permuted
               const float* __restrict__ Gt,              // 128x2048 f32 permuted
               float* __restrict__ c,                     // 128x512 f32
               unsigned short* __restrict__ hout,         // 128x512 bf16
               unsigned short* __restrict__ hsb,          // b-major hs
               int t)
{
  __shared__ char smem[98304];                          // 96 KB
  unsigned short* sA = (unsigned short*)smem;           // 128x256 bf16
  unsigned short* sB = (unsigned short*)(smem + 65536); // 64x256 bf16
  float* gl = (float*)smem;                             // 128x68 f32 (aliased)

  const int tid  = threadIdx.x;
  const int lane = tid & 63;
  const int wave = tid >> 6;
  const int wm   = wave & 1;    // M half (64 rows)
  const int wn   = wave >> 1;   // N half (32 cols)
  const int n0   = blockIdx.x * 64;

  const int lr = lane >> 5;     // row parity within instruction (2 rows x 32 chunks)
  const int lp = lane & 31;     // LDS chunk position

  f32x4 acc[4][2] = {};
  const int fm = lane & 15;
  const int q  = lane >> 4;

  for (int kt = 0; kt < 512; kt += 256) {
#pragma unroll
    for (int s = 0; s < 16; s++) {
      int row = wave * 32 + s * 2 + lr;           // hprev row within 128
      int gch = lp ^ (row & 7);                   // swizzled global chunk
      async16(hprev + (size_t)row * 512 + kt + gch * 8,
              sA + wave * 8192 + s * 512 + lane * 8);
    }
#pragma unroll
    for (int s = 0; s < 8; s++) {
      int row = wave * 16 + s * 2 + lr;           // Whh row within 64-tile
      int gch = lp ^ (row & 7);
      async16(Whh + (size_t)(n0 + row) * 512 + kt + gch * 8,
              sB + wave * 4096 + s * 512 + lane * 8);
    }
    __syncthreads();

#pragma unroll
    for (int kk = 0; kk < 8; kk++) {
      int ch = kk * 4 + q;
      short8 af[4], bfv[2];
#pragma unroll
      for (int i = 0; i < 4; i++) {
        int ra = wm * 64 + i * 16 + fm;
        af[i]  = *(const short8*)&sA[ra * 256 + ((ch ^ (ra & 7)) * 8)];
      }
#pragma unroll
      for (int j = 0; j < 2; j++) {
        int rb = wn * 32 + j * 16 + fm;
        bfv[j] = *(const short8*)&sB[rb * 256 + ((ch ^ (rb & 7)) * 8)];
      }
#pragma unroll
      for (int i = 0; i < 4; i++)
#pragma unroll
        for (int j = 0; j < 2; j++)
          acc[i][j] = __builtin_amdgcn_mfma_f32_16x16x32_bf16(af[i], bfv[j], acc[i][j], 0, 0, 0);
    }
    __syncthreads();
  }

  // accumulators -> aliased LDS gate buffer (ld=68 breaks bank alignment)
#pragma unroll
  for (int i = 0; i < 4; i++)
#pragma unroll
    for (int j = 0; j < 2; j++)
#pragma unroll
      for (int r = 0; r < 4; r++)
        gl[(wm * 64 + i * 16 + q * 4 + r) * 68 + wn * 32 + j * 16 + fm] = acc[i][j][r];
  __syncthreads();

  // pointwise: 128 rows x 16 local units (gates interleaved i,f,g,o per unit)
#pragma unroll
  for (int it = 0; it < 8; it++) {
    int p   = it * 256 + tid;
    int row = p >> 4;
    int ul  = p & 15;
    float4 a4 = *(float4*)&gl[row * 68 + ul * 4];
    float4 G4 = *(const float4*)&Gt[row * 2048 + n0 + ul * 4];
    float gi = a4.x + G4.x, gf = a4.y + G4.y, gg = a4.z + G4.z, go = a4.w + G4.w;
    int gu  = (n0 >> 2) + ul;
    int idx = row * 512 + gu;
    float cn = sigf(gf) * c[idx] + sigf(gi) * tanhfast(gg);
    c[idx] = cn;
    float hn = sigf(go) * tanhfast(cn);
    unsigned short h16 = f2b(hn);
    hout[idx] = h16;
    hsb[((size_t)row * T_ + t) * 512 + gu] = h16;
  }
}

// ---- t=0 pointwise (h0=c0=0) ----
__global__ void lstm_point0(const float* __restrict__ G0, float* __restrict__ c,
                            unsigned short* __restrict__ hb, unsigned short* __restrict__ hsb) {
  int idx = blockIdx.x * 256 + threadIdx.x;    // 128*512
  int b = idx >> 9, u = idx & 511;
  float4 g4 = ((const float4*)(G0 + (size_t)b * 2048))[u];
  float cn = sigf(g4.x) * tanhfast(g4.z);
  c[idx] = cn;
  float hn = sigf(g4.w) * tanhfast(cn);
  unsigned short h16 = f2b(hn);
  hb[idx] = h16;
  hsb[((size_t)b * T_ + 0) * 512 + u] = h16;
}

// ---- gate-interleave + bf16 convert for both W_ih and W_hh in one launch ----
__global__ void permute_cvt2(const float* __restrict__ Wih, const float* __restrict__ Whh,
                             unsigned short* __restrict__ dih, unsigned short* __restrict__ dhh) {
  int p = blockIdx.x;                           // 0..4095
  const float* src = (p < 2048) ? Wih : Whh;
  unsigned short* dst = (p < 2048) ? dih : dhh;
  int pp = p & 2047;
  int ir = ((pp & 3) << 9) + (pp >> 2);
  float4 v = ((const float4*)(src + (size_t)ir * 512))[threadIdx.x];   // 128 thr
  ushort4 o;
  o.x = f2b(v.x); o.y = f2b(v.y); o.z = f2b(v.z); o.w = f2b(v.w);
  ((ushort4*)(dst + (size_t)p * 512))[threadIdx.x] = o;
}

// ---- fp32 KxN -> bf16 NxK transpose+convert ----
__global__ void transpose_cvt(const float* __restrict__ src, unsigned short* __restrict__ dst,
                              int K, int N) {
  __shared__ float tile[32][33];
  int n0 = blockIdx.x * 32, k0 = blockIdx.y * 32;
  int tcol = threadIdx.x & 31, trow = threadIdx.x >> 5;
  for (int r = trow; r < 32; r += 8)
    tile[r][tcol] = src[(size_t)(k0 + r) * N + n0 + tcol];
  __syncthreads();
  for (int r = trow; r < 32; r += 8)
    dst[(size_t)(n0 + r) * K + k0 + tcol] = f2b(tile[tcol][r]);
}

// ---- encoder row (t=0 of x) ----
__global__ __launch_bounds__(256) void encode(const float* __restrict__ features,
                                              const float* __restrict__ W_enc,
                                              const float* __restrict__ b_enc,
                                              unsigned short* __restrict__ xb) {
  __shared__ float fs[512];
  int b = blockIdx.y, e = blockIdx.x * 256 + threadIdx.x;
  fs[threadIdx.x]       = features[b * 512 + threadIdx.x];
  fs[threadIdx.x + 256] = features[b * 512 + threadIdx.x + 256];
  __syncthreads();
  float acc = 0.f;
#pragma unroll 8
  for (int k = 0; k < 512; k++) acc += fs[k] * W_enc[(size_t)k * 512 + e];
  xb[(size_t)b * 512 + e] = f2b(acc + b_enc[e]);
}

// ---- embedding gather (t=1..16 of x, time-major) ----
__global__ void embed_k(const int* __restrict__ captions, const float* __restrict__ emb,
                        unsigned short* __restrict__ xb) {
  int t = blockIdx.x + 1, b = blockIdx.y;
  int tok = captions[b * T_ + (t - 1)];
  float4 v = ((const float4*)(emb + (size_t)tok * 512))[threadIdx.x];
  ushort4 o;
  o.x = f2b(v.x); o.y = f2b(v.y); o.z = f2b(v.z); o.w = f2b(v.w);
  ((ushort4*)(xb + (size_t)(t * B_ + b) * 512))[threadIdx.x] = o;
}

// ---- softmax from bf16 logits -> f32 probs ----
__global__ __launch_bounds__(1024) void softmax_b(const unsigned short* __restrict__ lg,
                                                  float* __restrict__ out) {
  __shared__ float ps[1024];
  const uint4* r4 = (const uint4*)(lg + (size_t)blockIdx.x * V_);   // 4000 uint4/row
  float* orow = out + (size_t)blockIdx.x * V_;
  int tid = threadIdx.x;
  float v[4][8];
  float s = 0.f;
#pragma unroll
  for (int u = 0; u < 4; u++) {
    int i = u * 1024 + tid;
    if (i < 4000) {
      uint4 w = r4[i];
      unsigned a[4] = {w.x, w.y, w.z, w.w};
#pragma unroll
      for (int k = 0; k < 4; k++) {
        float lo = __uint_as_float(a[k] << 16);
        float hi = __uint_as_float(a[k] & 0xffff0000u);
        float e0 = __expf(lo), e1 = __expf(hi);
        v[u][2 * k] = e0; v[u][2 * k + 1] = e1;
        s += e0 + e1;
      }
    }
  }
  ps[tid] = s;
  __syncthreads();
  for (int o = 512; o > 0; o >>= 1) {
    if (tid < o) ps[tid] += ps[tid + o];
    __syncthreads();
  }
  float inv = 1.f / ps[0];
#pragma unroll
  for (int u = 0; u < 4; u++) {
    int i = u * 1024 + tid;
    if (i < 4000) {
      float4 o1 = {v[u][0] * inv, v[u][1] * inv, v[u][2] * inv, v[u][3] * inv};
      float4 o2 = {v[u][4] * inv, v[u][5] * inv, v[u][6] * inv, v[u][7] * inv};
      ((float4*)(orow + (size_t)i * 8))[0] = o1;
      ((float4*)(orow + (size_t)i * 8))[1] = o2;
    }
  }
}

// ---- fallback: in-place f32 softmax ----
__global__ __launch_bounds__(1024) void softmax_f(float* __restrict__ out) {
  __shared__ float ps[1024];
  float* r = out + (size_t)blockIdx.x * V_;
  int tid = threadIdx.x;
  float v[32];
  float s = 0.f;
#pragma unroll
  for (int u = 0; u < 32; u++) {
    int i = u * 1024 + tid;
    if (i < V_) { float e = __expf(r[i]); v[u] = e; s += e; }
  }
  ps[tid] = s;
  __syncthreads();
  for (int o = 512; o > 0; o >>= 1) {
    if (tid < o) ps[tid] += ps[tid + o];
    __syncthreads();
  }
  float inv = 1.f / ps[0];
#pragma unroll
  for (int u = 0; u < 32; u++) {
    int i = u * 1024 + tid;
    if (i < V_) r[i] = v[u] * inv;
  }
}

extern "C" void kernel_launch(void* const* d_in, const int* in_sizes, int n_in,
                              void* d_out, int out_size, void* d_ws, size_t ws_size,
                              hipStream_t stream) {
  const float* features = (const float*)d_in[0];
  const int*   captions = (const int*)d_in[1];
  const float* W_enc  = (const float*)d_in[2];
  const float* b_enc  = (const float*)d_in[3];
  const float* emb    = (const float*)d_in[4];
  const float* W_ih   = (const float*)d_in[5];
  const float* b_ih   = (const float*)d_in[6];
  const float* W_hh   = (const float*)d_in[7];
  const float* b_hh   = (const float*)d_in[8];
  const float* W_d2   = (const float*)d_in[9];
  const float* b_d2   = (const float*)d_in[10];
  const float* W_last = (const float*)d_in[11];
  const float* b_last = (const float*)d_in[12];
  float* out = (float*)d_out;

  char* ws = (char*)d_ws;
  size_t off = 0;
  auto alloc = [&](size_t bytes) -> void* {
    void* p = ws + off;
    off += (bytes + 255) & ~(size_t)255;
    return p;
  };
  unsigned short* xb     = (unsigned short*)alloc((size_t)MR_ * E_ * 2);
  unsigned short* Wb_ih  = (unsigned short*)alloc((size_t)4 * H_ * E_ * 2);
  unsigned short* Wb_hh  = (unsigned short*)alloc((size_t)4 * H_ * H_ * 2);
  unsigned short* Wb_d2t = (unsigned short*)alloc((size_t)D2_ * H_ * 2);
  unsigned short* Wb_lt  = (unsigned short*)alloc((size_t)V_ * D2_ * 2);
  float*          G      = (float*)alloc((size_t)MR_ * 4 * H_ * 4);
  float*          cst    = (float*)alloc((size_t)B_ * H_ * 4);
  unsigned short* hb0    = (unsigned short*)alloc((size_t)B_ * H_ * 2);
  unsigned short* hb1    = (unsigned short*)alloc((size_t)B_ * H_ * 2);
  unsigned short* hsb    = (unsigned short*)alloc((size_t)MR_ * H_ * 2);
  unsigned short* outb   = (unsigned short*)alloc((size_t)MR_ * D2_ * 2);
  unsigned short* lgb    = (unsigned short*)alloc((size_t)MR_ * V_ * 2);
  const bool bf16_logits = (off <= ws_size);
  (void)in_sizes; (void)n_in; (void)out_size;

  // weight prep
  permute_cvt2<<<4096, 128, 0, stream>>>(W_ih, W_hh, Wb_ih, Wb_hh);
  transpose_cvt<<<dim3(D2_ / 32, H_ / 32), 256, 0, stream>>>(W_d2, Wb_d2t, H_, D2_);

  // x (bf16, time-major)
  encode<<<dim3(2, B_), 256, 0, stream>>>(features, W_enc, b_enc, xb);
  embed_k<<<dim3(T_ - 1, B_), 128, 0, stream>>>(captions, emb, xb);

  // G = x @ Wb_ih^T + (b_ih + b_hh), gate-interleaved columns
  gemm_bt<0, 0><<<17 * 16, 256, 0, stream>>>(xb, Wb_ih, G, b_ih, b_hh, 4 * H_, E_, 17, 17 * 16);

  // LSTM chain (fused, ping-pong h buffers; 32 blocks x 64 gate-cols)
  lstm_point0<<<B_ * H_ / 256, 256, 0, stream>>>(G, cst, hb0, hsb);
  for (int t = 1; t < T_; t++) {
    unsigned short* hp = (t & 1) ? hb0 : hb1;
    unsigned short* hc = (t & 1) ? hb1 : hb0;
    lstm_step<<<32, 256, 0, stream>>>(hp, Wb_hh, G + (size_t)t * B_ * 4 * H_, cst, hc, hsb, t);
  }

  // W_last transpose late so Wb_lt is L2/L3-warm for the big GEMM
  transpose_cvt<<<dim3(V_ / 32, D2_ / 32), 256, 0, stream>>>(W_last, Wb_lt, D2_, V_);

  // out = relu(hs @ W_d2 + b_d2) -> bf16 (b-major rows)
  gemm_bt<2, 0><<<17 * 8, 256, 0, stream>>>(hsb, Wb_d2t, outb, b_d2, nullptr, D2_, H_, 17, 17 * 8);

  // logits = out @ W_last + b_last: 256^2-tile pipelined GEMM, then softmax
  const int nbm2   = 9;                            // ceil(2176/256), last tile clamps
  const int nwork2 = nbm2 * (V_ / 256);            // 1125
  const int per2   = (nwork2 + 7) / 8;             // 141
  if (bf16_logits) {
    gemm256<3><<<8 * per2, 512, 0, stream>>>(outb, Wb_lt, lgb, b_last, V_, D2_, MR_, nbm2, nwork2);
    softmax_b<<<MR_, 1024, 0, stream>>>(lgb, out);
  } else {
    gemm256<4><<<8 * per2, 512, 0, stream>>>(outb, Wb_lt, out, b_last, V_, D2_, MR_, nbm2, nwork2);
    softmax_f<<<MR_, 1024, 0, stream>>>(out);
  }
}